// Round 8
// baseline (168.024 us; speedup 1.0000x reference)
//
#include <hip/hip_runtime.h>
#include <hip/hip_fp16.h>

#define B 64
#define N 4096
#define M 128

constexpr int T   = 1024;          // 16 waves, 1 block/CU (128 KiB LDS)
constexpr int CPB = 16;            // -> 8 packed complex planes, 2 groups x 4
constexpr int NWG = B * (M / CPB); // 512 blocks

// low-3 XOR fold: spreads slot%8 (the ds_*_b128 bank-group class) for all
// stage strides and for digit-reversed unpack rows. Bijective.
__device__ __forceinline__ int sidx(int p) {
    return (p & ~7) | ((p ^ (p >> 3) ^ (p >> 6) ^ (p >> 9)) & 7);
}
// octal-digit reverse of 12-bit index (DIF output slot of frequency k)
__device__ __forceinline__ int rev12(int k) {
    return ((k & 7) << 9) | (((k >> 3) & 7) << 6) | (((k >> 6) & 7) << 3) | ((k >> 9) & 7);
}

__device__ __forceinline__ float2 cadd(float2 a, float2 b){ return make_float2(a.x+b.x, a.y+b.y); }
__device__ __forceinline__ float2 csub(float2 a, float2 b){ return make_float2(a.x-b.x, a.y-b.y); }
__device__ __forceinline__ float2 cmul(float2 a, float2 b){ return make_float2(a.x*b.x - a.y*b.y, a.x*b.y + a.y*b.x); }
__device__ __forceinline__ float2 mulnegi(float2 a){ return make_float2(a.y, -a.x); }
__device__ __forceinline__ float2 muli(float2 a)  { return make_float2(-a.y, a.x); }
__device__ __forceinline__ float2 cis(float ang){ float s, c; __sincosf(ang, &s, &c); return make_float2(c, s); }
__device__ __forceinline__ float2 h2f(__half2 h){ return __half22float2(h); }
__device__ __forceinline__ __half2 f2h(float2 v){ return __floats2half2_rn(v.x, v.y); }
__device__ __forceinline__ unsigned h2u(__half2 h){ return *(unsigned*)&h; }
__device__ __forceinline__ __half2 u2h(unsigned u){ return *(__half2*)&u; }

// forward DFT8 in place (W8 = e^{-i pi/4})
__device__ __forceinline__ void dft8(float2 t[8]) {
    float2 e0=cadd(t[0],t[4]), e1=csub(t[0],t[4]);
    float2 e2=cadd(t[2],t[6]), e3=csub(t[2],t[6]);
    float2 E0=cadd(e0,e2), E2=csub(e0,e2);
    float2 E1=cadd(e1,mulnegi(e3)), E3=cadd(e1,muli(e3));
    float2 o0=cadd(t[1],t[5]), o1=csub(t[1],t[5]);
    float2 o2=cadd(t[3],t[7]), o3=csub(t[3],t[7]);
    float2 O0=cadd(o0,o2), O2=csub(o0,o2);
    float2 O1=cadd(o1,mulnegi(o3)), O3=cadd(o1,muli(o3));
    const float C = 0.70710678118654752f;
    float2 w1O1 = make_float2(C*(O1.x+O1.y), C*(O1.y-O1.x));
    float2 w2O2 = mulnegi(O2);
    float2 w3O3 = make_float2(C*(O3.y-O3.x), -C*(O3.x+O3.y));
    t[0]=cadd(E0,O0);   t[4]=csub(E0,O0);
    t[1]=cadd(E1,w1O1); t[5]=csub(E1,w1O1);
    t[2]=cadd(E2,w2O2); t[6]=csub(E2,w2O2);
    t[3]=cadd(E3,w3O3); t[7]=csub(E3,w3O3);
}

// One radix-8 DIF stage, span S. 1024 tasks = 2 groups x 512 butterflies.
// Each leg is a b128 over 4 planes; in-place on identical slots per task.
template<int S>
__device__ __forceinline__ void stage(uint4* zp, int tid) {
    const int g  = tid >> 9;
    const int qq = tid & 511;
    int G, j;
    if      (S == 512) { G = 0;               j = qq;      }
    else if (S == 64)  { G = (qq >> 6) << 9;  j = qq & 63; }
    else if (S == 8)   { G = (qq >> 3) << 6;  j = qq & 7;  }
    else               { G = qq << 3;         j = 0;       }
    const int base = g << 12;
    int idx[8];
    uint4 leg[8];
    #pragma unroll
    for (int c = 0; c < 8; ++c) {
        idx[c] = base + sidx(G + j + c * S);
        leg[c] = zp[idx[c]];
    }
    float2 w[8];
    if (S > 1) {
        float2 w1 = cis(-6.2831853071795864f * (float)j / (float)(8 * S));
        w[1] = w1;
        #pragma unroll
        for (int k = 2; k < 8; ++k) w[k] = cmul(w[k-1], w1);
    }
    #pragma unroll
    for (int pl = 0; pl < 4; ++pl) {
        float2 t[8];
        #pragma unroll
        for (int c = 0; c < 8; ++c) t[c] = h2f(u2h(((unsigned*)&leg[c])[pl]));
        dft8(t);
        if (S > 1) {
            #pragma unroll
            for (int k = 1; k < 8; ++k) t[k] = cmul(t[k], w[k]);
        }
        #pragma unroll
        for (int c = 0; c < 8; ++c) ((unsigned*)&leg[c])[pl] = h2u(f2h(t[c]));
    }
    #pragma unroll
    for (int c = 0; c < 8; ++c) zp[idx[c]] = leg[c];
}

__global__ __launch_bounds__(T, 4)
void fft_one(const float* __restrict__ x, float* __restrict__ out) {
    extern __shared__ __align__(16) unsigned char lds_raw[];
    uint4* zp = (uint4*)lds_raw;     // [2 grp][4096 slot][4 planes half2] = 128 KiB
    uint2* z2 = (uint2*)lds_raw;     // b64 view: planes {0,1} / {2,3} of a slot

    // decode: bid%8 = XCD = b low3 -> all 8 channel-groups of batch b co-XCD
    const int bid = blockIdx.x;
    const int b  = ((bid >> 6) << 3) | (bid & 7);
    const int m0 = ((bid >> 3) & 7) * CPB;
    const float* xb = x + (size_t)b * N * M + m0;
    const int tid = threadIdx.x;

    // ---- load: full 64B row segments; pack ch pairs -> planes, b64 LDS writes ----
    #pragma unroll
    for (int it = 0; it < 16; ++it) {
        int i = tid + (it << 10);        // 0..16383
        int n = i >> 2, c = i & 3;
        float4 v = *(const float4*)(xb + (size_t)n * M + (c << 2));
        int g = c >> 1, h = c & 1;
        uint2 wv;
        wv.x = h2u(f2h(make_float2(v.x, v.y)));   // plane 2c
        wv.y = h2u(f2h(make_float2(v.z, v.w)));   // plane 2c+1
        z2[(g << 13) + sidx(n) * 2 + h] = wv;
    }
    __syncthreads();

    // ---- 4 radix-8 DIF stages: natural in -> digit-reversed out ----
    stage<512>(zp, tid); __syncthreads();
    stage<64 >(zp, tid); __syncthreads();
    stage<8  >(zp, tid); __syncthreads();
    stage<1  >(zp, tid); __syncthreads();

    // ---- Hermitian unpack (freq k at slot rev12(k)) + full 64B segment stores ----
    float* outRe = out;
    float* outIm = out + (size_t)B * N * M;
    const size_t rbase = (size_t)b * N * M + m0;
    #pragma unroll
    for (int it = 0; it < 16; ++it) {
        int u = tid + (it << 10);
        int k = u >> 2, c = u & 3;
        int kk = (N - k) & (N - 1);
        int g = c >> 1, h = c & 1;
        int sk  = sidx(rev12(k));
        int smk = sidx(rev12(kk));
        uint2 a  = z2[(g << 13) + sk  * 2 + h];
        uint2 bq = z2[(g << 13) + smk * 2 + h];
        float2 Zk0 = h2f(u2h(a.x)),  Zk1 = h2f(u2h(a.y));
        float2 Zm0 = h2f(u2h(bq.x)), Zm1 = h2f(u2h(bq.y));
        float4 re, im;
        re.x = 0.5f * (Zk0.x + Zm0.x); im.x = 0.5f * (Zk0.y - Zm0.y);
        re.y = 0.5f * (Zk0.y + Zm0.y); im.y = 0.5f * (Zm0.x - Zk0.x);
        re.z = 0.5f * (Zk1.x + Zm1.x); im.z = 0.5f * (Zk1.y - Zm1.y);
        re.w = 0.5f * (Zk1.y + Zm1.y); im.w = 0.5f * (Zm1.x - Zk1.x);
        *(float4*)(outRe + rbase + (size_t)k * M + (c << 2)) = re;
        *(float4*)(outIm + rbase + (size_t)k * M + (c << 2)) = im;
    }
}

extern "C" void kernel_launch(void* const* d_in, const int* in_sizes, int n_in,
                              void* d_out, int out_size, void* d_ws, size_t ws_size,
                              hipStream_t stream) {
    const float* x = (const float*)d_in[0];
    float* out = (float*)d_out;
    const int lds_bytes = 2 * N * 16;   // 131072
    hipFuncSetAttribute((const void*)fft_one,
                        hipFuncAttributeMaxDynamicSharedMemorySize, lds_bytes);
    fft_one<<<NWG, T, lds_bytes, stream>>>(x, out);
}